// Round 1
// baseline (218.752 us; speedup 1.0000x reference)
//
#include <hip/hip_runtime.h>
#include <stdint.h>

#define DN 128
#define AN 128
#define HN 4
#define FN 128
#define L2N 50
#define NPOS (64*200)
#define NEGC (-4294967295.0f)

// ws layout (4B units)
#define OFF_MTWB 0         // u32 [40 tn][4 kk][64 lane][4 jj] : B-frag MT|Wf pairs along dd
#define OFF_GTB  40960     // u32 [8 tn][16 kk][64 lane][4 jj] : B-frag GT pairs along flat hd
#define OFF_CB   73728     // f32 [640] : 0..511 = Wk_h^T bq ; 512..639 = bv@Wf+bf
#define OFF_U    74368     // u32 [12800][256] : u as half2 pairs along outc
#define OFF_R    3351168   // f32 [12800][128] : qe@Wf + B0
#define OFF_PV   4989568   // u32 [12800][256] : pv as half2 pairs, flat hd

typedef __fp16 half2v __attribute__((ext_vector_type(2)));
typedef __fp16 f16x8  __attribute__((ext_vector_type(8)));
typedef float  f32x4  __attribute__((ext_vector_type(4)));
union frg { uint4 u; f16x8 h; };

__device__ __forceinline__ float dot2(uint32_t a, uint32_t b, float c) {
#if __has_builtin(__builtin_amdgcn_fdot2)
    union { uint32_t u; half2v h; } ca, cb; ca.u = a; cb.u = b;
    return __builtin_amdgcn_fdot2(ca.h, cb.h, c, false);
#else
    union { uint32_t u; _Float16 h[2]; } ca, cb; ca.u = a; cb.u = b;
    return c + (float)ca.h[0]*(float)cb.h[0] + (float)ca.h[1]*(float)cb.h[1];
#endif
}
__device__ __forceinline__ uint32_t packh2(float x, float y) {   // RTNE
    union { _Float16 h[2]; uint32_t u; } c; c.h[0] = (_Float16)x; c.h[1] = (_Float16)y;
    return c.u;
}
__device__ __forceinline__ float lo16f(uint32_t u) {
    union { uint32_t u; _Float16 h[2]; } c; c.u = u; return (float)c.h[0];
}
__device__ __forceinline__ float hi16f(uint32_t u) {
    union { uint32_t u; _Float16 h[2]; } c; c.u = u; return (float)c.h[1];
}

// ================= K0: fold weights into MFMA-B-fragment order =================
__global__ __launch_bounds__(256) void k0_pre(
    const float* __restrict__ Wq, const float* __restrict__ bq,
    const float* __restrict__ Wk, const float* __restrict__ bk,
    const float* __restrict__ Wv, const float* __restrict__ bv,
    const float* __restrict__ Wf, const float* __restrict__ bfb,
    float* __restrict__ ws)
{
    uint32_t* MTWB = (uint32_t*)ws + OFF_MTWB;
    uint32_t* GTBw = (uint32_t*)ws + OFF_GTB;
    float*    CB   = ws + OFF_CB;
    const int idx = blockIdx.x*256 + threadIdx.x;

    if (idx < 40960) {                       // MTWB: pairs along dd
        int jj = idx & 3, lane = (idx>>2)&63, kk = (idx>>8)&3, tn = idx>>10;
        int outc = tn*16 + (lane&15);
        int dd2  = kk*16 + (lane>>4)*4 + jj;
        int dd0  = 2*dd2, dd1 = dd0+1;
        float s0, s1;
        if (outc < 512) {                    // MT[dd][outc] = Wq[dd]_h . Wk[d]_h
            int h = outc >> 7, d = outc & 127;
            const float* wk = Wk + d*AN + h*32;
            const float* q0 = Wq + dd0*AN + h*32;
            const float* q1 = Wq + dd1*AN + h*32;
            s0 = 0.f; s1 = 0.f;
            #pragma unroll 8
            for (int j = 0; j < 32; ++j) { float w = wk[j]; s0 += q0[j]*w; s1 += q1[j]*w; }
        } else {                             // Wf[dd][f]
            int f = outc - 512;
            s0 = Wf[dd0*FN + f]; s1 = Wf[dd1*FN + f];
        }
        MTWB[idx] = packh2(s0, s1);
    } else if (idx < 73728) {                // GTB: pairs along flat hd
        int i2 = idx - 40960;
        int jj = i2 & 3, lane = (i2>>2)&63, kk = (i2>>8)&15, tn = i2>>12;
        int f  = tn*16 + (lane&15);
        int j2 = kk*16 + (lane>>4)*4 + jj;
        int hd0 = 2*j2;
        int h = hd0 >> 7, d0 = hd0 & 127, d1 = d0+1;
        const float* v0 = Wv + d0*AN + h*32;
        const float* v1 = Wv + d1*AN + h*32;
        float s0 = 0.f, s1 = 0.f;
        #pragma unroll 8
        for (int a = 0; a < 32; ++a) {
            float wf = Wf[(h*32+a)*FN + f];
            s0 += v0[a]*wf; s1 += v1[a]*wf;
        }
        GTBw[i2] = packh2(s0, s1);
    } else {                                 // CB
        int c = idx - 73728;
        if (c < 512) {                       // Wk_h^T bq
            int h = c >> 7, d = c & 127;
            float s = 0.f;
            #pragma unroll 8
            for (int j = 0; j < 32; ++j) s += Wk[d*AN + h*32 + j]*bq[h*32 + j];
            CB[c] = s;
        } else if (c < 640) {                // B0 = bv@Wf + bf
            int f = c - 512;
            float s = bfb[f];
            for (int a = 0; a < AN; ++a) s += bv[a]*Wf[a*FN + f];
            CB[c] = s;
        }
    }
}

// ================= K1: MFMA GEMM  U|R = qe @ [MT|Wf] + CB =================
__global__ __launch_bounds__(256) void k1_proj(
    const int* __restrict__ queries, const float* __restrict__ E,
    float* __restrict__ ws)
{
    const uint32_t* MTWB = (const uint32_t*)ws + OFF_MTWB;
    const float*    CB   = ws + OFF_CB;
    uint32_t* U = (uint32_t*)ws + OFF_U;
    float*    R = ws + OFF_R;

    const int t = threadIdx.x, wv = t >> 6, ln = t & 63;
    const int W  = blockIdx.x*4 + wv;          // 4000 waves
    const int tm = W / 5, g = W - tm*5;        // m-tile, n-group (8 tiles)
    const int m = ln & 15, q = ln >> 4;
    const int pos0 = tm*16 + q*4;

    const int qidx = queries[tm*16 + m];
    const float* Eq = E + (size_t)qidx * DN;

    frg a[4];
    #pragma unroll
    for (int kk = 0; kk < 4; ++kk) {           // A-frag: lane m=row, q*8 k-offset
        float4 e0 = *(const float4*)(Eq + kk*32 + q*8);
        float4 e1 = *(const float4*)(Eq + kk*32 + q*8 + 4);
        a[kk].u.x = packh2(e0.x, e0.y);
        a[kk].u.y = packh2(e0.z, e0.w);
        a[kk].u.z = packh2(e1.x, e1.y);
        a[kk].u.w = packh2(e1.z, e1.w);
    }

    #pragma unroll 1
    for (int i = 0; i < 8; ++i) {
        const int tn = g*8 + i;
        const float cb = CB[tn*16 + m];
        f32x4 c = {cb, cb, cb, cb};
        #pragma unroll
        for (int kk = 0; kk < 4; ++kk) {
            frg b; b.u = *(const uint4*)(MTWB + ((size_t)(tn*4 + kk)*64 + ln)*4);
            c = __builtin_amdgcn_mfma_f32_16x16x32_f16(a[kk].h, b.h, c, 0, 0, 0);
        }
        if (tn < 32) {                         // U: pack (outc,outc+1) via lane^1
            float p0 = __shfl_xor(c[0], 1);
            float p1 = __shfl_xor(c[1], 1);
            float p2 = __shfl_xor(c[2], 1);
            float p3 = __shfl_xor(c[3], 1);
            if ((ln & 1) == 0) {
                const int ucol = tn*8 + (m >> 1);
                U[(size_t)(pos0+0)*256 + ucol] = packh2(c[0], p0);
                U[(size_t)(pos0+1)*256 + ucol] = packh2(c[1], p1);
                U[(size_t)(pos0+2)*256 + ucol] = packh2(c[2], p2);
                U[(size_t)(pos0+3)*256 + ucol] = packh2(c[3], p3);
            }
        } else {                               // R: f32, D-layout
            const int f = (tn - 32)*16 + m;
            R[(size_t)(pos0+0)*128 + f] = c[0];
            R[(size_t)(pos0+1)*128 + f] = c[1];
            R[(size_t)(pos0+2)*128 + f] = c[2];
            R[(size_t)(pos0+3)*128 + f] = c[3];
        }
    }
}

// ================= K2: attention core v3 — MFMA QK^T, 1 wave/position =================
// 4 independent waves per block (no __syncthreads). Per wave:
//   1. stage U row (1 KB) into padded LDS (B-fragment source)
//   2. QK^T via 16x16x32 f16 MFMA: A = k_emb gathered in A-frag layout,
//      B cols 0..3 = U (heads), col 4 = f16 ones -> ksum (padding mask), cols 5..15 = 0
//   3. re-gather k_emb into dim-pair kreg (L2 hits) for scalar PV
//   4. softmax across C-fragment rows (keys) per column (head); weights -> f32 LDS
//   5. scalar PV over kreg + broadcast LDS weight reads
__global__ __launch_bounds__(256, 4) void k2_attn(
    const int* __restrict__ keys, const float* __restrict__ E,
    float* __restrict__ ws)
{
    __shared__ __align__(16) uint32_t U_s[4][272];      // [wave][h*68 + d2] padded stride 68
    __shared__ __align__(16) float    attnT[4][50][4];  // [wave][key][head], f32

    const uint32_t* U  = (const uint32_t*)ws + OFF_U;
    uint32_t*       PV = (uint32_t*)ws + OFF_PV;

    const int t = threadIdx.x, wv = t >> 6, ln = t & 63;
    const int pos = blockIdx.x*4 + wv;
    const int n = ln & 15, qd = ln >> 4;

    // ---- stage U row into padded LDS (pairs along dims, head-major) ----
    {
        uint4 uv = ((const uint4*)(U + (size_t)pos*256))[ln];
        *(uint4*)&U_s[wv][qd*68 + (n<<2)] = uv;
    }

    const int* kptr = keys + (size_t)pos*L2N;

    // ---- A-frag key ids (lane m = n selects key within 16-row tile) ----
    int km[4];
    #pragma unroll
    for (int mt = 0; mt < 4; ++mt) {
        int kid = mt*16 + n;
        km[mt] = kptr[kid < L2N ? kid : 0];
    }

    // ---- QK^T + ksum via MFMA ----
    f32x4 c[4];
    #pragma unroll
    for (int mt = 0; mt < 4; ++mt) c[mt] = (f32x4){0.f, 0.f, 0.f, 0.f};

    {
        float4 e0[4], e1[4];
        #pragma unroll
        for (int mt = 0; mt < 4; ++mt) {
            const float* ep = E + (size_t)km[mt]*DN + (qd<<3);
            e0[mt] = *(const float4*)ep;
            e1[mt] = *(const float4*)(ep + 4);
        }
        #pragma unroll
        for (int kk = 0; kk < 4; ++kk) {
            float4 ne0[4], ne1[4];
            if (kk < 3) {
                #pragma unroll
                for (int mt = 0; mt < 4; ++mt) {
                    const float* ep = E + (size_t)km[mt]*DN + (kk+1)*32 + (qd<<3);
                    ne0[mt] = *(const float4*)ep;
                    ne1[mt] = *(const float4*)(ep + 4);
                }
            }
            frg b;
            if (n < 4) {
                b.u = *(const uint4*)&U_s[wv][n*68 + kk*16 + (qd<<2)];
            } else if (n == 4) {
                b.u.x = 0x3C003C00u; b.u.y = 0x3C003C00u;
                b.u.z = 0x3C003C00u; b.u.w = 0x3C003C00u;   // f16 ones -> ksum column
            } else {
                b.u.x = 0u; b.u.y = 0u; b.u.z = 0u; b.u.w = 0u;
            }
            #pragma unroll
            for (int mt = 0; mt < 4; ++mt) {
                frg a;
                a.u.x = packh2(e0[mt].x, e0[mt].y);
                a.u.y = packh2(e0[mt].z, e0[mt].w);
                a.u.z = packh2(e1[mt].x, e1[mt].y);
                a.u.w = packh2(e1[mt].z, e1[mt].w);
                c[mt] = __builtin_amdgcn_mfma_f32_16x16x32_f16(a.h, b.h, c[mt], 0, 0, 0);
            }
            if (kk < 3) {
                #pragma unroll
                for (int mt = 0; mt < 4; ++mt) { e0[mt] = ne0[mt]; e1[mt] = ne1[mt]; }
            }
        }
    }

    // ---- gather-1: kreg in dim-pair layout for PV (L2 hits; 8-deep pipeline) ----
    uint32_t kreg[L2N];
    {
        const float* Eb = E + 2*ln;
        float2 f[8];
        #pragma unroll
        for (int r = 0; r < 8; ++r) f[r] = *(const float2*)(Eb + (size_t)kptr[r]*DN);
        #pragma unroll
        for (int r = 0; r < L2N; ++r) {
            float2 cur = f[r & 7];
            if (r + 8 < L2N) f[r & 7] = *(const float2*)(Eb + (size_t)kptr[r+8]*DN);
            kreg[r] = packh2(cur.x, cur.y);
        }
    }

    // ---- softmax over keys (C-rows) per column; overlaps kreg load latency ----
    {
        float sc[4][4];
        float mx = -__builtin_inff();
        #pragma unroll
        for (int mt = 0; mt < 4; ++mt) {
            #pragma unroll
            for (int j = 0; j < 4; ++j) {
                float ksv = __shfl(c[mt][j], (ln & 48) | 4);   // ksum lives in col-4 lane
                float v = c[mt][j] * 0.17677669529663687f;
                v = (ksv == 0.0f) ? NEGC : v;
                int key = mt*16 + (qd<<2) + j;
                if (key >= L2N) v = -__builtin_inff();
                sc[mt][j] = v;
                mx = fmaxf(mx, v);
            }
        }
        mx = fmaxf(mx, __shfl_xor(mx, 16));
        mx = fmaxf(mx, __shfl_xor(mx, 32));
        float e[4][4];
        float sum = 0.f;
        #pragma unroll
        for (int mt = 0; mt < 4; ++mt) {
            #pragma unroll
            for (int j = 0; j < 4; ++j) {
                float ev = __expf(sc[mt][j] - mx);
                e[mt][j] = ev; sum += ev;
            }
        }
        sum += __shfl_xor(sum, 16);
        sum += __shfl_xor(sum, 32);
        const float inv = 1.0f / sum;
        if (n < 4) {
            #pragma unroll
            for (int mt = 0; mt < 4; ++mt) {
                #pragma unroll
                for (int j = 0; j < 4; ++j) {
                    int key = mt*16 + (qd<<2) + j;
                    if (key < L2N) attnT[wv][key][n] = e[mt][j] * inv;
                }
            }
        }
    }

    // ---- PV: lane = dim-pair, broadcast f32 weight reads ----
    {
        float pa0=0.f,pb0=0.f,pa1=0.f,pb1=0.f,pa2=0.f,pb2=0.f,pa3=0.f,pb3=0.f;
        #pragma unroll
        for (int r = 0; r < L2N; ++r) {
            float4 w4 = *(const float4*)&attnT[wv][r][0];
            uint32_t kp = kreg[r];
            float kx = lo16f(kp), ky = hi16f(kp);
            pa0 += w4.x*kx; pb0 += w4.x*ky;
            pa1 += w4.y*kx; pb1 += w4.y*ky;
            pa2 += w4.z*kx; pb2 += w4.z*ky;
            pa3 += w4.w*kx; pb3 += w4.w*ky;
        }
        uint32_t* PVp = PV + (size_t)pos*256;
        PVp[0*64 + ln] = packh2(pa0, pb0);
        PVp[1*64 + ln] = packh2(pa1, pb1);
        PVp[2*64 + ln] = packh2(pa2, pb2);
        PVp[3*64 + ln] = packh2(pa3, pb3);
    }
}

// ================= K3: MFMA GEMM  out = PV @ GT + R =================
__global__ __launch_bounds__(256) void k3_out(
    const float* __restrict__ ws, float* __restrict__ out)
{
    const uint32_t* GTB = (const uint32_t*)ws + OFF_GTB;
    const uint32_t* PV  = (const uint32_t*)ws + OFF_PV;
    const float*    R   = ws + OFF_R;

    const int t = threadIdx.x, wv = t >> 6, ln = t & 63;
    const int W  = blockIdx.x*4 + wv;          // 3200 waves
    const int tm = W >> 2, g = W & 3;          // m-tile, n-group (2 tiles)
    const int m = ln & 15, q = ln >> 4;
    const int pos0 = tm*16 + q*4;

    frg a[16];
    const uint32_t* PVa = PV + (size_t)(tm*16 + m)*256;
    #pragma unroll
    for (int kk = 0; kk < 16; ++kk)
        a[kk].u = *(const uint4*)(PVa + kk*16 + q*4);

    #pragma unroll 1
    for (int i = 0; i < 2; ++i) {
        const int nt = g*2 + i;
        const int f = nt*16 + m;
        f32x4 c;
        c[0] = R[(size_t)(pos0+0)*128 + f];
        c[1] = R[(size_t)(pos0+1)*128 + f];
        c[2] = R[(size_t)(pos0+2)*128 + f];
        c[3] = R[(size_t)(pos0+3)*128 + f];
        #pragma unroll
        for (int kk = 0; kk < 16; ++kk) {
            frg b; b.u = *(const uint4*)(GTB + ((size_t)(nt*16 + kk)*64 + ln)*4);
            c = __builtin_amdgcn_mfma_f32_16x16x32_f16(a[kk].h, b.h, c, 0, 0, 0);
        }
        out[(size_t)(pos0+0)*128 + f] = c[0];
        out[(size_t)(pos0+1)*128 + f] = c[1];
        out[(size_t)(pos0+2)*128 + f] = c[2];
        out[(size_t)(pos0+3)*128 + f] = c[3];
    }
}

extern "C" void kernel_launch(void* const* d_in, const int* in_sizes, int n_in,
                              void* d_out, int out_size, void* d_ws, size_t ws_size,
                              hipStream_t stream) {
    const int* queries = (const int*)d_in[0];
    const int* keys    = (const int*)d_in[1];
    const float* E   = (const float*)d_in[2];
    const float* Wq  = (const float*)d_in[3];
    const float* bq  = (const float*)d_in[4];
    const float* Wk  = (const float*)d_in[5];
    const float* bk  = (const float*)d_in[6];
    const float* Wv  = (const float*)d_in[7];
    const float* bv  = (const float*)d_in[8];
    const float* Wf  = (const float*)d_in[9];
    const float* bfb = (const float*)d_in[10];
    float* ws = (float*)d_ws;
    float* o  = (float*)d_out;

    hipLaunchKernelGGL(k0_pre,  dim3(291),  dim3(256), 0, stream,
                       Wq, bq, Wk, bk, Wv, bv, Wf, bfb, ws);
    hipLaunchKernelGGL(k1_proj, dim3(1000), dim3(256), 0, stream, queries, E, ws);
    hipLaunchKernelGGL(k2_attn, dim3(3200), dim3(256), 0, stream, keys, E, ws);
    hipLaunchKernelGGL(k3_out,  dim3(800),  dim3(256), 0, stream, ws, o);
}